// Round 1
// baseline (2826.498 us; speedup 1.0000x reference)
//
#include <hip/hip_runtime.h>

// ConcentrationPredictor: 32 RK4 steps of dc/dt = flux(c) with per-cell MLP
// diffusion coefficient. Halo-fused S_FUSE steps per launch.

constexpr int TPB    = 256;              // threads per block = region cells (1 cell/thread)
constexpr int S_FUSE = 4;                // RK4 steps fused per launch
constexpr int HALO   = 4 * S_FUSE;       // validity shrinks 4 cells/side per RK4 step
constexpr int B_INNER = TPB - 2 * HALO;  // cells written per block (224)

__device__ __forceinline__ float fast_tanh(float x) {
    // tanh(x) = 1 - 2/(1+e^{2x}); graceful at +-inf (e->inf => 1, e->0 => -1)
    float e = __expf(2.0f * x);
    return 1.0f - 2.0f * __builtin_amdgcn_rcpf(1.0f + e);
}

__device__ __forceinline__ float fast_sigmoid(float x) {
    return __builtin_amdgcn_rcpf(1.0f + __expf(-x));
}

// MLP [1,15,15,15,1]: tanh hidden, sigmoid out. Weights row-major [fan_in][fan_out].
__device__ __forceinline__ float mlp_ret(
    float x,
    const float* __restrict__ W1, const float* __restrict__ b1,
    const float* __restrict__ W2, const float* __restrict__ b2,
    const float* __restrict__ W3, const float* __restrict__ b3,
    const float* __restrict__ W4, const float* __restrict__ b4)
{
    float h[15], h2[15];
#pragma unroll
    for (int j = 0; j < 15; ++j)
        h[j] = fast_tanh(fmaf(x, W1[j], b1[j]));
#pragma unroll
    for (int j = 0; j < 15; ++j) {
        float a = b2[j];
#pragma unroll
        for (int k = 0; k < 15; ++k) a = fmaf(h[k], W2[k * 15 + j], a);
        h2[j] = fast_tanh(a);
    }
#pragma unroll
    for (int j = 0; j < 15; ++j) {
        float a = b3[j];
#pragma unroll
        for (int k = 0; k < 15; ++k) a = fmaf(h2[k], W3[k * 15 + j], a);
        h[j] = fast_tanh(a);
    }
    float o = b4[0];
#pragma unroll
    for (int k = 0; k < 15; ++k) o = fmaf(h[k], W4[k], o);
    return fast_sigmoid(o);
}

__device__ __forceinline__ float flux_cell(float ret, float c, float cl, float cr,
                                           int g, int N)
{
    const float D0   = 0.3125f;  // 0.0005 / 0.04^2 (f32-rounds to exactly 0.3125)
    const float DXc  = 0.04f;
    const float BC00 = 1.0f;
    if (g == 0) {
        return D0 * ret * ((BC00 - c) + (cr - c));
    } else if (g == N - 1) {
        float rbc = D0 * DXc * (cl - c);
        return D0 * ret * ((cl - c) + (rbc - c));
    }
    return D0 * ret * (cl + cr - 2.0f * c);
}

__global__ __launch_bounds__(TPB)
void rk4_steps_kernel(const float* __restrict__ src,   // state at step s0 [N]
                      float* __restrict__ out,         // [T, N]
                      const float* __restrict__ t,
                      const float* __restrict__ W1, const float* __restrict__ b1,
                      const float* __restrict__ W2, const float* __restrict__ b2,
                      const float* __restrict__ W3, const float* __restrict__ b3,
                      const float* __restrict__ W4, const float* __restrict__ b4,
                      const float* __restrict__ p_exp,
                      int N, int s0, int nsub)
{
    __shared__ float la[TPB];
    __shared__ float lb[TPB];

    const int tid = threadIdx.x;
    const int g   = blockIdx.x * B_INNER - HALO + tid;  // my global cell (may be OOB)
    const int gi  = min(max(g, 0), N - 1);              // clamped load index

    const float scale = powf(10.0f, p_exp[0]);

    float c = src[gi];

    const int tl = (tid > 0) ? tid - 1 : 0;
    const int tr = (tid < TPB - 1) ? tid + 1 : TPB - 1;

    for (int s = 0; s < nsub; ++s) {
        const float dt = t[s0 + s + 1] - t[s0 + s];

        // stage 1
        la[tid] = c;
        __syncthreads();
        float cl = la[tl], cr = la[tr];
        float k1 = flux_cell(mlp_ret(c * scale, W1, b1, W2, b2, W3, b3, W4, b4),
                             c, cl, cr, g, N);
        float c2 = fmaf(0.5f * dt, k1, c);

        // stage 2
        lb[tid] = c2;
        __syncthreads();
        cl = lb[tl]; cr = lb[tr];
        float k2 = flux_cell(mlp_ret(c2 * scale, W1, b1, W2, b2, W3, b3, W4, b4),
                             c2, cl, cr, g, N);
        float c3 = fmaf(0.5f * dt, k2, c);

        // stage 3
        la[tid] = c3;
        __syncthreads();
        cl = la[tl]; cr = la[tr];
        float k3 = flux_cell(mlp_ret(c3 * scale, W1, b1, W2, b2, W3, b3, W4, b4),
                             c3, cl, cr, g, N);
        float c4 = fmaf(dt, k3, c);

        // stage 4
        lb[tid] = c4;
        __syncthreads();
        cl = lb[tl]; cr = lb[tr];
        float k4 = flux_cell(mlp_ret(c4 * scale, W1, b1, W2, b2, W3, b3, W4, b4),
                             c4, cl, cr, g, N);

        c = fmaf(dt / 6.0f, k1 + 2.0f * k2 + 2.0f * k3 + k4, c);

        // write valid inner window of this step's new state
        if (tid >= HALO && tid < HALO + B_INNER && g < N)
            out[(size_t)(s0 + s + 1) * N + g] = c;
    }
}

extern "C" void kernel_launch(void* const* d_in, const int* in_sizes, int n_in,
                              void* d_out, int out_size, void* d_ws, size_t ws_size,
                              hipStream_t stream)
{
    const float* c0    = (const float*)d_in[0];
    const float* t     = (const float*)d_in[1];
    const float* W1    = (const float*)d_in[2];
    const float* b1    = (const float*)d_in[3];
    const float* W2    = (const float*)d_in[4];
    const float* b2    = (const float*)d_in[5];
    const float* W3    = (const float*)d_in[6];
    const float* b3    = (const float*)d_in[7];
    const float* W4    = (const float*)d_in[8];
    const float* b4    = (const float*)d_in[9];
    const float* p_exp = (const float*)d_in[10];

    float* out = (float*)d_out;

    const int N      = in_sizes[0];       // 65536
    const int nsteps = in_sizes[1] - 1;   // 32

    // row 0 = c0
    hipMemcpyAsync(out, c0, (size_t)N * sizeof(float),
                   hipMemcpyDeviceToDevice, stream);

    const int grid = (N + B_INNER - 1) / B_INNER;  // 293

    for (int s0 = 0; s0 < nsteps; s0 += S_FUSE) {
        const int nsub = min(S_FUSE, nsteps - s0);
        const float* src = (s0 == 0) ? c0 : out + (size_t)s0 * N;
        hipLaunchKernelGGL(rk4_steps_kernel, dim3(grid), dim3(TPB), 0, stream,
                           src, out, t,
                           W1, b1, W2, b2, W3, b3, W4, b4, p_exp,
                           N, s0, nsub);
    }
}

// Round 2
// 459.272 us; speedup vs baseline: 6.1543x; 6.1543x over previous
//
#include <hip/hip_runtime.h>

// ConcentrationPredictor: 32 RK4 steps of dc/dt = flux(c) with per-cell MLP
// diffusion coefficient. Halo-fused S_FUSE steps per launch.
// R2: all MLP weights staged in LDS (broadcast reads), W2/W3 transposed so the
// inner-k loop is contiguous (ds_read_b128-able).

constexpr int TPB    = 256;              // threads per block = region cells (1 cell/thread)
constexpr int S_FUSE = 4;                // RK4 steps fused per launch
constexpr int HALO   = 4 * S_FUSE;       // validity shrinks 4 cells/side per RK4 step
constexpr int B_INNER = TPB - 2 * HALO;  // cells written per block (224)

// LDS weight layout offsets (floats)
constexpr int O_W1  = 0;     // [15]
constexpr int O_B1  = 15;    // [15]
constexpr int O_W2T = 30;    // [15][15]  w2t[j*15+k] = W2[k*15+j]
constexpr int O_B2  = 255;   // [15]
constexpr int O_W3T = 270;   // [15][15]
constexpr int O_B3  = 495;   // [15]
constexpr int O_W4  = 510;   // [15]
constexpr int O_B4  = 525;   // [1]
constexpr int WTOT  = 526;

__device__ __forceinline__ float fast_tanh(float x) {
    // tanh(x) = 1 - 2/(1+e^{2x}); graceful at +-inf
    float e = __expf(2.0f * x);
    return 1.0f - 2.0f * __builtin_amdgcn_rcpf(1.0f + e);
}

__device__ __forceinline__ float fast_sigmoid(float x) {
    return __builtin_amdgcn_rcpf(1.0f + __expf(-x));
}

// MLP [1,15,15,15,1]: tanh hidden, sigmoid out. w points at LDS block above.
__device__ __forceinline__ float mlp_ret(float x, const float* w)
{
    float h[15], h2[15];
#pragma unroll
    for (int j = 0; j < 15; ++j)
        h[j] = fast_tanh(fmaf(x, w[O_W1 + j], w[O_B1 + j]));
#pragma unroll
    for (int j = 0; j < 15; ++j) {
        float a = w[O_B2 + j];
#pragma unroll
        for (int k = 0; k < 15; ++k) a = fmaf(h[k], w[O_W2T + j * 15 + k], a);
        h2[j] = fast_tanh(a);
    }
#pragma unroll
    for (int j = 0; j < 15; ++j) {
        float a = w[O_B3 + j];
#pragma unroll
        for (int k = 0; k < 15; ++k) a = fmaf(h2[k], w[O_W3T + j * 15 + k], a);
        h[j] = fast_tanh(a);
    }
    float o = w[O_B4];
#pragma unroll
    for (int k = 0; k < 15; ++k) o = fmaf(h[k], w[O_W4 + k], o);
    return fast_sigmoid(o);
}

__device__ __forceinline__ float flux_cell(float ret, float c, float cl, float cr,
                                           int g, int N)
{
    const float D0   = 0.3125f;  // 0.0005 / 0.04^2 (exact in f32)
    const float DXc  = 0.04f;
    const float BC00 = 1.0f;
    if (g == 0) {
        return D0 * ret * ((BC00 - c) + (cr - c));
    } else if (g == N - 1) {
        float rbc = D0 * DXc * (cl - c);
        return D0 * ret * ((cl - c) + (rbc - c));
    }
    return D0 * ret * (cl + cr - 2.0f * c);
}

__global__ __launch_bounds__(TPB)
void rk4_steps_kernel(const float* __restrict__ src,   // state at step s0 [N]
                      float* __restrict__ out,         // [T, N]
                      const float* __restrict__ t,
                      const float* __restrict__ W1, const float* __restrict__ b1,
                      const float* __restrict__ W2, const float* __restrict__ b2,
                      const float* __restrict__ W3, const float* __restrict__ b3,
                      const float* __restrict__ W4, const float* __restrict__ b4,
                      const float* __restrict__ p_exp,
                      int N, int s0, int nsub)
{
    __shared__ float la[TPB];
    __shared__ float lb[TPB];
    __shared__ float w[WTOT];

    const int tid = threadIdx.x;

    // ---- stage weights into LDS (transposing W2/W3) ----
    if (tid < 15) {
        w[O_W1 + tid] = W1[tid];
        w[O_B1 + tid] = b1[tid];
        w[O_B2 + tid] = b2[tid];
        w[O_B3 + tid] = b3[tid];
        w[O_W4 + tid] = W4[tid];
    }
    if (tid < 225) {
        const int k = tid / 15, j = tid % 15;
        w[O_W2T + j * 15 + k] = W2[tid];
        w[O_W3T + j * 15 + k] = W3[tid];
    }
    if (tid == 0) w[O_B4] = b4[0];

    const int g  = blockIdx.x * B_INNER - HALO + tid;  // my global cell (may be OOB)
    const int gi = min(max(g, 0), N - 1);              // clamped load index

    const float scale = powf(10.0f, p_exp[0]);

    float c = src[gi];

    const int tl = (tid > 0) ? tid - 1 : 0;
    const int tr = (tid < TPB - 1) ? tid + 1 : TPB - 1;

    for (int s = 0; s < nsub; ++s) {
        const float dt = t[s0 + s + 1] - t[s0 + s];

        // stage 1 (this first barrier also covers the weight staging)
        la[tid] = c;
        __syncthreads();
        float cl = la[tl], cr = la[tr];
        float k1 = flux_cell(mlp_ret(c * scale, w), c, cl, cr, g, N);
        float c2 = fmaf(0.5f * dt, k1, c);

        // stage 2
        lb[tid] = c2;
        __syncthreads();
        cl = lb[tl]; cr = lb[tr];
        float k2 = flux_cell(mlp_ret(c2 * scale, w), c2, cl, cr, g, N);
        float c3 = fmaf(0.5f * dt, k2, c);

        // stage 3
        la[tid] = c3;
        __syncthreads();
        cl = la[tl]; cr = la[tr];
        float k3 = flux_cell(mlp_ret(c3 * scale, w), c3, cl, cr, g, N);
        float c4 = fmaf(dt, k3, c);

        // stage 4
        lb[tid] = c4;
        __syncthreads();
        cl = lb[tl]; cr = lb[tr];
        float k4 = flux_cell(mlp_ret(c4 * scale, w), c4, cl, cr, g, N);

        c = fmaf(dt / 6.0f, k1 + 2.0f * k2 + 2.0f * k3 + k4, c);

        // write valid inner window of this step's new state
        if (tid >= HALO && tid < HALO + B_INNER && g < N)
            out[(size_t)(s0 + s + 1) * N + g] = c;
    }
}

extern "C" void kernel_launch(void* const* d_in, const int* in_sizes, int n_in,
                              void* d_out, int out_size, void* d_ws, size_t ws_size,
                              hipStream_t stream)
{
    const float* c0    = (const float*)d_in[0];
    const float* t     = (const float*)d_in[1];
    const float* W1    = (const float*)d_in[2];
    const float* b1    = (const float*)d_in[3];
    const float* W2    = (const float*)d_in[4];
    const float* b2    = (const float*)d_in[5];
    const float* W3    = (const float*)d_in[6];
    const float* b3    = (const float*)d_in[7];
    const float* W4    = (const float*)d_in[8];
    const float* b4    = (const float*)d_in[9];
    const float* p_exp = (const float*)d_in[10];

    float* out = (float*)d_out;

    const int N      = in_sizes[0];       // 65536
    const int nsteps = in_sizes[1] - 1;   // 32

    // row 0 = c0
    hipMemcpyAsync(out, c0, (size_t)N * sizeof(float),
                   hipMemcpyDeviceToDevice, stream);

    const int grid = (N + B_INNER - 1) / B_INNER;  // 293

    for (int s0 = 0; s0 < nsteps; s0 += S_FUSE) {
        const int nsub = min(S_FUSE, nsteps - s0);
        const float* src = (s0 == 0) ? c0 : out + (size_t)s0 * N;
        hipLaunchKernelGGL(rk4_steps_kernel, dim3(grid), dim3(TPB), 0, stream,
                           src, out, t,
                           W1, b1, W2, b2, W3, b3, W4, b4, p_exp,
                           N, s0, nsub);
    }
}